// Round 4
// baseline (864.950 us; speedup 1.0000x reference)
//
#include <hip/hip_runtime.h>

typedef __bf16 bf16x8 __attribute__((ext_vector_type(8)));
typedef float floatx4 __attribute__((ext_vector_type(4)));
typedef unsigned short ushort8 __attribute__((ext_vector_type(8)));
typedef unsigned short ushort4v __attribute__((ext_vector_type(4)));

#define MFMA(a, b, c) __builtin_amdgcn_mfma_f32_16x16x32_bf16((a), (b), (c), 0, 0, 0)

__device__ __forceinline__ unsigned short f2bf(float x) {
  union { float f; unsigned u; } v; v.f = x;
  unsigned r = v.u + 0x7FFFu + ((v.u >> 16) & 1u);  // RNE; inputs finite
  return (unsigned short)(r >> 16);
}

// ---------------------------------------------------------------------------
// prep: K -> bf16 tiles, V -> TRANSPOSED bf16 tiles, LINEAR layout.
// Tile = 64 rows x 64 bf16 (128 B row). Chunk g = r*8+s holds elems s*8..s*8+7
// of row r.  K tile (b,h,mt): row r = key m = mt*64+r, row axis = d.
//            V tile (b,h,mt): row r = d,              row axis = m (V^T).
// ---------------------------------------------------------------------------
__global__ __launch_bounds__(256)
void prep(const float* __restrict__ K, const float* __restrict__ V,
          unsigned short* __restrict__ Kb, unsigned short* __restrict__ Vt)
{
  int id = blockIdx.x * 256 + threadIdx.x;   // 0 .. 2*524288-1
  int isV = id >> 19;
  int cch = id & 524287;                     // chunk id within K or V half
  int bh = cch >> 14;                        // b*8+h  (32*512 chunks per bh)
  int mt = (cch >> 9) & 31;
  int g  = cch & 511;
  int r  = g >> 3;
  int s  = g & 7;                            // 8-elem group along the row axis
  int b = bh >> 3, h = bh & 7;
  ushort8 o;
  if (!isV) {
    const float* p = K + (((size_t)(b * 2048 + mt * 64 + r) * 8 + h) * 64 + s * 8);
    float4 x0 = *(const float4*)p;
    float4 x1 = *(const float4*)(p + 4);
    o[0] = f2bf(x0.x); o[1] = f2bf(x0.y); o[2] = f2bf(x0.z); o[3] = f2bf(x0.w);
    o[4] = f2bf(x1.x); o[5] = f2bf(x1.y); o[6] = f2bf(x1.z); o[7] = f2bf(x1.w);
    *(ushort8*)(Kb + (size_t)cch * 8) = o;
  } else {
    const float* p = V + (((size_t)(b * 2048 + mt * 64 + s * 8) * 8 + h) * 64 + r);
    #pragma unroll
    for (int j = 0; j < 8; ++j) o[j] = f2bf(p[(size_t)j * 512]);
    *(ushort8*)(Vt + (size_t)cch * 8) = o;
  }
}

// 16B fragment read from a linear [64][64] bf16 tile in GLOBAL memory
__device__ __forceinline__ bf16x8 gfrag(const unsigned short* tile, int r, int e)
{
  return *(const bf16x8*)(tile + r * 64 + e);
}

__global__ __launch_bounds__(256, 4)
void attn_fwd(const float* __restrict__ Q, const unsigned short* __restrict__ Kb,
              const unsigned short* __restrict__ Vt,
              float* __restrict__ outQV, float* __restrict__ outA)
{
  // Only LDS use: P lane-shuffle bounce, wave-private rows, XOR-swizzled.
  __shared__ __align__(16) unsigned short As[4096];   // [64 rows][128 B]

  const int tid = threadIdx.x;
  const int w  = tid >> 6;   // wave 0..3 -> q rows [16w,16w+16)
  const int l  = tid & 63;
  const int c  = l & 15;
  const int q4 = l >> 4;

  // bijective XCD chunk swizzle: grid 1024 = 8 XCDs x 128; XCD k owns 4 whole (b,h)
  const int bx = (blockIdx.x & 7) * 128 + (blockIdx.x >> 3);
  const int qt = bx & 31;
  const int h  = (bx >> 5) & 7;
  const int b  = bx >> 8;
  const int q0 = qt * 64;

  const float scale = 0.125f * 1.44269504088896340736f;  // 1/sqrt(64) * log2(e)

  const size_t base = (size_t)b * (2048 * 512) + (size_t)h * 64;  // + n*512 + d
  const float* Qb = Q + base + (size_t)q0 * 512;

  const unsigned short* Kt0 = Kb + (size_t)(b * 8 + h) * (32 * 4096);
  const unsigned short* Vt0 = Vt + (size_t)(b * 8 + h) * (32 * 4096);

  // ---- Q fragments straight to registers (B-operand of swapped QK^T) ----
  bf16x8 bQ0, bQ1;
  {
    const float* qp = Qb + (size_t)(16 * w + c) * 512 + q4 * 8;
    float4 qa0 = *(const float4*)(qp);
    float4 qa1 = *(const float4*)(qp + 4);
    float4 qb0 = *(const float4*)(qp + 32);
    float4 qb1 = *(const float4*)(qp + 36);
    ushort8 t0, t1;
    t0[0]=f2bf(qa0.x*scale); t0[1]=f2bf(qa0.y*scale); t0[2]=f2bf(qa0.z*scale); t0[3]=f2bf(qa0.w*scale);
    t0[4]=f2bf(qa1.x*scale); t0[5]=f2bf(qa1.y*scale); t0[6]=f2bf(qa1.z*scale); t0[7]=f2bf(qa1.w*scale);
    t1[0]=f2bf(qb0.x*scale); t1[1]=f2bf(qb0.y*scale); t1[2]=f2bf(qb0.z*scale); t1[3]=f2bf(qb0.w*scale);
    t1[4]=f2bf(qb1.x*scale); t1[5]=f2bf(qb1.y*scale); t1[6]=f2bf(qb1.z*scale); t1[7]=f2bf(qb1.w*scale);
    bQ0 = __builtin_bit_cast(bf16x8, t0);
    bQ1 = __builtin_bit_cast(bf16x8, t1);
  }

  // ---- pass 1: per-row sum of exp2(S). No LDS, no barriers: waves free-run. ----
  float lsum[4] = {0.f, 0.f, 0.f, 0.f};
  for (int mt = 0; mt < 32; ++mt) {
    const unsigned short* gK = Kt0 + (size_t)mt * 4096;
    #pragma unroll
    for (int t = 0; t < 4; ++t) {
      bf16x8 aK0 = gfrag(gK, t * 16 + c, q4 * 8);
      bf16x8 aK1 = gfrag(gK, t * 16 + c, 32 + q4 * 8);
      floatx4 acc = {0.f, 0.f, 0.f, 0.f};
      acc = MFMA(aK0, bQ0, acc);   // swapped: lane holds S[q=16w+c][m=t*16+q4*4+i]
      acc = MFMA(aK1, bQ1, acc);
      #pragma unroll
      for (int i = 0; i < 4; ++i) lsum[i] += __builtin_amdgcn_exp2f(acc[i]);
    }
  }
  float rs = (lsum[0] + lsum[1]) + (lsum[2] + lsum[3]);
  rs += __shfl_xor(rs, 16);
  rs += __shfl_xor(rs, 32);
  const float rcp = 1.0f / rs;

  // ---- pass 2: recompute S, write A, accumulate O = A*V. Still barrier-free. ----
  floatx4 Oacc[4];
  #pragma unroll
  for (int t = 0; t < 4; ++t) Oacc[t] = (floatx4){0.f, 0.f, 0.f, 0.f};

  const int arow = 16 * w + c;
  float* aRowP = outA + (((size_t)(b * 8 + h) * 2048 + q0 + arow) * 2048) + q4 * 4;

  for (int mt = 0; mt < 32; ++mt) {
    const unsigned short* gK = Kt0 + (size_t)mt * 4096;
    const unsigned short* gV = Vt0 + (size_t)mt * 4096;
    const int mc = mt * 64;
    #pragma unroll
    for (int t = 0; t < 4; ++t) {
      bf16x8 aK0 = gfrag(gK, t * 16 + c, q4 * 8);
      bf16x8 aK1 = gfrag(gK, t * 16 + c, 32 + q4 * 8);
      floatx4 acc = {0.f, 0.f, 0.f, 0.f};
      acc = MFMA(aK0, bQ0, acc);
      acc = MFMA(aK1, bQ1, acc);
      floatx4 av;
      av[0] = __builtin_amdgcn_exp2f(acc[0]) * rcp;
      av[1] = __builtin_amdgcn_exp2f(acc[1]) * rcp;
      av[2] = __builtin_amdgcn_exp2f(acc[2]) * rcp;
      av[3] = __builtin_amdgcn_exp2f(acc[3]) * rcp;
      *(floatx4*)(aRowP + mc + t * 16) = av;   // L2 write-combines to full lines
      // As[arow][t*16 + q4*4 .. +3], 16B-slot XOR swizzle (conflict-free b64 writes)
      ushort4v us = { f2bf(av[0]), f2bf(av[1]), f2bf(av[2]), f2bf(av[3]) };
      int bo = t * 32 + q4 * 8;                // byte col within row
      int slot = ((bo >> 4) ^ arow) & 7;
      *(ushort4v*)((char*)As + arow * 128 + (slot << 4) + (bo & 15)) = us;
    }
    // PV: aP = own wave's P rows (same-wave LDS RAW; compiler inserts lgkmcnt wait)
    {
      int s0 = (((q4 * 16) >> 4) ^ arow) & 7;
      int s1 = (((64 + q4 * 16) >> 4) ^ arow) & 7;
      bf16x8 aP0 = *(const bf16x8*)((const char*)As + arow * 128 + (s0 << 4));
      bf16x8 aP1 = *(const bf16x8*)((const char*)As + arow * 128 + (s1 << 4));
      #pragma unroll
      for (int t = 0; t < 4; ++t) {
        bf16x8 bV0 = gfrag(gV, t * 16 + c, q4 * 8);
        bf16x8 bV1 = gfrag(gV, t * 16 + c, 32 + q4 * 8);
        Oacc[t] = MFMA(aP0, bV0, Oacc[t]);
        Oacc[t] = MFMA(aP1, bV1, Oacc[t]);
      }
    }
  }

  // ---- write queried_values [B,N,H,D] ----
  #pragma unroll
  for (int t = 0; t < 4; ++t) {
    #pragma unroll
    for (int i = 0; i < 4; ++i) {
      outQV[base + (size_t)(q0 + 16 * w + q4 * 4 + i) * 512 + t * 16 + c] = Oacc[t][i];
    }
  }
}

extern "C" void kernel_launch(void* const* d_in, const int* in_sizes, int n_in,
                              void* d_out, int out_size, void* d_ws, size_t ws_size,
                              hipStream_t stream)
{
  const float* Q = (const float*)d_in[0];
  const float* K = (const float*)d_in[1];
  const float* V = (const float*)d_in[2];
  float* outQV = (float*)d_out;                 // [4,2048,8,64] = 4194304 floats
  float* outA  = (float*)d_out + 4194304;       // [4,8,2048,2048]

  unsigned short* Kb = (unsigned short*)d_ws;           // 8 MB bf16 K tiles (linear)
  unsigned short* Vt = (unsigned short*)d_ws + 4194304; // 8 MB bf16 V^T tiles (linear)

  prep<<<dim3(4096), dim3(256), 0, stream>>>(K, V, Kb, Vt);
  attn_fwd<<<dim3(1024), dim3(256), 0, stream>>>(Q, Kb, Vt, outQV, outA);
}

// Round 5
// 636.112 us; speedup vs baseline: 1.3597x; 1.3597x over previous
//
#include <hip/hip_runtime.h>

typedef __bf16 bf16x8 __attribute__((ext_vector_type(8)));
typedef float floatx4 __attribute__((ext_vector_type(4)));
typedef unsigned short ushort8 __attribute__((ext_vector_type(8)));
typedef unsigned short ushort4v __attribute__((ext_vector_type(4)));

#define MFMA(a, b, c) __builtin_amdgcn_mfma_f32_16x16x32_bf16((a), (b), (c), 0, 0, 0)

__device__ __forceinline__ unsigned short f2bf(float x) {
  union { float f; unsigned u; } v; v.f = x;
  unsigned r = v.u + 0x7FFFu + ((v.u >> 16) & 1u);  // RNE; inputs finite
  return (unsigned short)(r >> 16);
}

// ---------------------------------------------------------------------------
// prep: K -> bf16 tiles, V -> TRANSPOSED bf16 tiles, both pre-swizzled.
// Tile = 64 rows x 128 B (64 bf16). Global chunk g = r*8+s (16 B) holds the
// original bytes [(s ^ (r&7))*16 .. +15] of row r, so a LINEAR
// global_load_lds lands them XOR-swizzled in LDS (rule #21 involution).
// K tile (b,h,mt): row r = key m = mt*64+r, row axis = d (64 bf16).
// V tile (b,h,mt): row r = d,              row axis = m (64 bf16), i.e. V^T.
// ---------------------------------------------------------------------------
__global__ __launch_bounds__(256)
void prep(const float* __restrict__ K, const float* __restrict__ V,
          unsigned short* __restrict__ Kb, unsigned short* __restrict__ Vt)
{
  int id = blockIdx.x * 256 + threadIdx.x;   // 0 .. 2*524288-1
  int isV = id >> 19;
  int cch = id & 524287;                     // chunk id within K or V half
  int bh = cch >> 14;                        // b*8+h  (32*512 chunks per bh)
  int mt = (cch >> 9) & 31;
  int g  = cch & 511;
  int r  = g >> 3;
  int s  = g & 7;
  int e8 = s ^ (r & 7);                      // 8-elem group along the row axis
  int b = bh >> 3, h = bh & 7;
  ushort8 o;
  if (!isV) {
    const float* p = K + (((size_t)(b * 2048 + mt * 64 + r) * 8 + h) * 64 + e8 * 8);
    float4 x0 = *(const float4*)p;
    float4 x1 = *(const float4*)(p + 4);
    o[0] = f2bf(x0.x); o[1] = f2bf(x0.y); o[2] = f2bf(x0.z); o[3] = f2bf(x0.w);
    o[4] = f2bf(x1.x); o[5] = f2bf(x1.y); o[6] = f2bf(x1.z); o[7] = f2bf(x1.w);
    *(ushort8*)(Kb + (size_t)cch * 8) = o;
  } else {
    const float* p = V + (((size_t)(b * 2048 + mt * 64 + e8 * 8) * 8 + h) * 64 + r);
    #pragma unroll
    for (int j = 0; j < 8; ++j) o[j] = f2bf(p[(size_t)j * 512]);
    *(ushort8*)(Vt + (size_t)cch * 8) = o;
  }
}

// 8-wave cooperative stage: wave w DMAs its 1 KB slice of an 8 KB tile (1 vmem op)
__device__ __forceinline__ void stage1k(const unsigned short* gsrc, unsigned short* lds,
                                        int w, int l)
{
  const char* g = (const char*)gsrc + w * 1024 + l * 16;
  char* sd = (char*)lds + w * 1024;
  __builtin_amdgcn_global_load_lds((const __attribute__((address_space(1))) unsigned int*)g,
                                   (__attribute__((address_space(3))) unsigned int*)sd, 16, 0, 0);
}

// swizzled 16B fragment read from a [64][128B] tile; bo = original byte col (16B-mult)
__device__ __forceinline__ bf16x8 frag(const unsigned short* lds, int r, int bo)
{
  int slot = ((bo >> 4) ^ r) & 7;
  return *(const bf16x8*)((const char*)lds + r * 128 + (slot << 4));
}

__global__ __launch_bounds__(512, 4)
void attn_fwd(const float* __restrict__ Q, const unsigned short* __restrict__ Kb,
              const unsigned short* __restrict__ Vt,
              float* __restrict__ outQV, float* __restrict__ outA)
{
  __shared__ __align__(16) unsigned short Ks[3][4096];   // 3-deep K tiles (8 KB each)
  __shared__ __align__(16) unsigned short Vs[3][4096];   // 3-deep V^T tiles
  __shared__ __align__(16) unsigned short As[8192];      // P bounce [128 rows][128 B], swizzled
  // total 64 KB -> 2 blocks/CU (grid = 2/CU exactly), 16 waves/CU

  const int tid = threadIdx.x;
  const int w  = tid >> 6;   // wave 0..7 -> q rows [16w,16w+16)
  const int l  = tid & 63;
  const int c  = l & 15;
  const int q4 = l >> 4;

  // bijective XCD chunk swizzle: grid 512 = 8 XCDs x 64; XCD k owns 4 whole (b,h)
  const int bx = (blockIdx.x & 7) * 64 + (blockIdx.x >> 3);
  const int qt = bx & 15;
  const int bh = bx >> 4;
  const int h  = bh & 7;
  const int b  = bh >> 3;
  const int q0 = qt * 128;

  const float scale = 0.125f * 1.44269504088896340736f;  // 1/sqrt(64) * log2(e)

  const size_t base = (size_t)b * (2048 * 512) + (size_t)h * 64;  // + n*512 + d
  const float* Qb = Q + base + (size_t)q0 * 512;

  const unsigned short* Kt0 = Kb + (size_t)bh * (32 * 4096);
  const unsigned short* Vt0 = Vt + (size_t)bh * (32 * 4096);

  // ---- Q fragments straight to registers (B-operand of swapped QK^T) ----
  bf16x8 bQ0, bQ1;
  {
    const float* qp = Qb + (size_t)(16 * w + c) * 512 + q4 * 8;
    float4 qa0 = *(const float4*)(qp);
    float4 qa1 = *(const float4*)(qp + 4);
    float4 qb0 = *(const float4*)(qp + 32);
    float4 qb1 = *(const float4*)(qp + 36);
    ushort8 t0, t1;
    t0[0]=f2bf(qa0.x*scale); t0[1]=f2bf(qa0.y*scale); t0[2]=f2bf(qa0.z*scale); t0[3]=f2bf(qa0.w*scale);
    t0[4]=f2bf(qa1.x*scale); t0[5]=f2bf(qa1.y*scale); t0[6]=f2bf(qa1.z*scale); t0[7]=f2bf(qa1.w*scale);
    t1[0]=f2bf(qb0.x*scale); t1[1]=f2bf(qb0.y*scale); t1[2]=f2bf(qb0.z*scale); t1[3]=f2bf(qb0.w*scale);
    t1[4]=f2bf(qb1.x*scale); t1[5]=f2bf(qb1.y*scale); t1[6]=f2bf(qb1.z*scale); t1[7]=f2bf(qb1.w*scale);
    bQ0 = __builtin_bit_cast(bf16x8, t0);
    bQ1 = __builtin_bit_cast(bf16x8, t1);
  }

  // ---- pass 1: per-row sum of exp2(S); K triple-buffered, stage mt+2 ahead ----
  stage1k(Kt0, Ks[0], w, l);
  stage1k(Kt0 + 4096, Ks[1], w, l);
  asm volatile("s_waitcnt vmcnt(1)" ::: "memory");   // stage(0) landed
  __builtin_amdgcn_s_barrier();
  __builtin_amdgcn_sched_barrier(0);

  float lsum[4] = {0.f, 0.f, 0.f, 0.f};
  int cur = 0;
  for (int mt = 0; mt < 32; ++mt) {
    int nx = (mt + 2 < 32) ? mt + 2 : 31;          // clamped redundant re-stage keeps op shape
    int sb = cur + 2; if (sb >= 3) sb -= 3;
    stage1k(Kt0 + (size_t)nx * 4096, Ks[sb], w, l);
    __builtin_amdgcn_sched_barrier(0);             // pin stage before everything else
    const unsigned short* Kc = Ks[cur];
    __builtin_amdgcn_s_setprio(1);
    #pragma unroll
    for (int t = 0; t < 4; ++t) {
      bf16x8 aK0 = frag(Kc, t * 16 + c, q4 * 16);
      bf16x8 aK1 = frag(Kc, t * 16 + c, 64 + q4 * 16);
      floatx4 acc = {0.f, 0.f, 0.f, 0.f};
      acc = MFMA(aK0, bQ0, acc);   // swapped: lane holds S[q=16w+c][m=t*16+q4*4+i]
      acc = MFMA(aK1, bQ1, acc);
      #pragma unroll
      for (int i = 0; i < 4; ++i) lsum[i] += __builtin_amdgcn_exp2f(acc[i]);
    }
    __builtin_amdgcn_s_setprio(0);
    // bottom: force stage(mt+1) (oldest outstanding); stage(mt+2) stays in flight
    __builtin_amdgcn_sched_barrier(0);
    asm volatile("s_waitcnt vmcnt(1)" ::: "memory");
    __builtin_amdgcn_s_barrier();
    __builtin_amdgcn_sched_barrier(0);
    cur = cur + 1; if (cur >= 3) cur -= 3;
  }
  float rs = (lsum[0] + lsum[1]) + (lsum[2] + lsum[3]);
  rs += __shfl_xor(rs, 16);
  rs += __shfl_xor(rs, 32);
  const float rcp = 1.0f / rs;

  // ---- pass 2: recompute S, write A, accumulate O = A*V ----
  floatx4 Oacc[4];
  #pragma unroll
  for (int t = 0; t < 4; ++t) Oacc[t] = (floatx4){0.f, 0.f, 0.f, 0.f};

  const int arow = 16 * w + c;
  float* aRowP = outA + (((size_t)bh * 2048 + q0 + arow) * 2048) + q4 * 4;

  // drain pass-1 leftovers: redundant stage of buf0 must not overlap re-stage of buf0
  asm volatile("s_waitcnt vmcnt(0)" ::: "memory");
  stage1k(Kt0, Ks[0], w, l);
  stage1k(Vt0, Vs[0], w, l);
  stage1k(Kt0 + 4096, Ks[1], w, l);
  stage1k(Vt0 + 4096, Vs[1], w, l);
  asm volatile("s_waitcnt vmcnt(2)" ::: "memory");   // tile-0 K+V landed
  __builtin_amdgcn_s_barrier();
  __builtin_amdgcn_sched_barrier(0);

  cur = 0;
  for (int mt = 0; mt < 32; ++mt) {
    int nx = (mt + 2 < 32) ? mt + 2 : 31;
    int sb = cur + 2; if (sb >= 3) sb -= 3;
    stage1k(Kt0 + (size_t)nx * 4096, Ks[sb], w, l);
    stage1k(Vt0 + (size_t)nx * 4096, Vs[sb], w, l);
    __builtin_amdgcn_sched_barrier(0);             // pin [stage 2] before [stores 4]
    const unsigned short* Kc = Ks[cur];
    const unsigned short* Vc = Vs[cur];
    const int mc = mt * 64;
    __builtin_amdgcn_s_setprio(1);
    #pragma unroll
    for (int t = 0; t < 4; ++t) {
      bf16x8 aK0 = frag(Kc, t * 16 + c, q4 * 16);
      bf16x8 aK1 = frag(Kc, t * 16 + c, 64 + q4 * 16);
      floatx4 acc = {0.f, 0.f, 0.f, 0.f};
      acc = MFMA(aK0, bQ0, acc);
      acc = MFMA(aK1, bQ1, acc);
      floatx4 av;
      av[0] = __builtin_amdgcn_exp2f(acc[0]) * rcp;
      av[1] = __builtin_amdgcn_exp2f(acc[1]) * rcp;
      av[2] = __builtin_amdgcn_exp2f(acc[2]) * rcp;
      av[3] = __builtin_amdgcn_exp2f(acc[3]) * rcp;
      *(floatx4*)(aRowP + mc + t * 16) = av;       // cached store; L2 merges to full lines
      // As[arow][t*16 + q4*4 .. +3], 16B-slot XOR swizzle (b64 writes)
      ushort4v us = { f2bf(av[0]), f2bf(av[1]), f2bf(av[2]), f2bf(av[3]) };
      int bo = t * 32 + q4 * 8;                    // byte col within row
      int slot = ((bo >> 4) ^ arow) & 7;
      *(ushort4v*)((char*)As + arow * 128 + (slot << 4) + (bo & 15)) = us;
    }
    // PV: aP = own wave's P rows (same-wave LDS RAW; compiler inserts lgkmcnt wait)
    {
      int s0 = ((q4) ^ arow) & 7;                  // (q4*16)>>4 = q4
      int s1 = ((4 + q4) ^ arow) & 7;              // (64+q4*16)>>4 = 4+q4
      bf16x8 aP0 = *(const bf16x8*)((const char*)As + arow * 128 + (s0 << 4));
      bf16x8 aP1 = *(const bf16x8*)((const char*)As + arow * 128 + (s1 << 4));
      #pragma unroll
      for (int t = 0; t < 4; ++t) {
        bf16x8 bV0 = frag(Vc, t * 16 + c, q4 * 16);
        bf16x8 bV1 = frag(Vc, t * 16 + c, 64 + q4 * 16);
        Oacc[t] = MFMA(aP0, bV0, Oacc[t]);
        Oacc[t] = MFMA(aP1, bV1, Oacc[t]);
      }
    }
    __builtin_amdgcn_s_setprio(0);
    // bottom: vmcnt(6) leaves [stage(mt+2) 2, stores(mt) 4] in flight; forces
    // stage(mt+1) + stores(mt-1). Verified at prologue transition and tail.
    __builtin_amdgcn_sched_barrier(0);
    asm volatile("s_waitcnt vmcnt(6)" ::: "memory");
    __builtin_amdgcn_s_barrier();
    __builtin_amdgcn_sched_barrier(0);
    cur = cur + 1; if (cur >= 3) cur -= 3;
  }

  // ---- write queried_values [B,N,H,D] ----
  #pragma unroll
  for (int t = 0; t < 4; ++t) {
    #pragma unroll
    for (int i = 0; i < 4; ++i) {
      outQV[base + (size_t)(q0 + 16 * w + q4 * 4 + i) * 512 + t * 16 + c] = Oacc[t][i];
    }
  }
}

extern "C" void kernel_launch(void* const* d_in, const int* in_sizes, int n_in,
                              void* d_out, int out_size, void* d_ws, size_t ws_size,
                              hipStream_t stream)
{
  const float* Q = (const float*)d_in[0];
  const float* K = (const float*)d_in[1];
  const float* V = (const float*)d_in[2];
  float* outQV = (float*)d_out;                 // [4,2048,8,64] = 4194304 floats
  float* outA  = (float*)d_out + 4194304;       // [4,8,2048,2048]

  unsigned short* Kb = (unsigned short*)d_ws;           // 8 MB swizzled bf16 K tiles
  unsigned short* Vt = (unsigned short*)d_ws + 4194304; // 8 MB swizzled bf16 V^T tiles

  prep<<<dim3(4096), dim3(256), 0, stream>>>(K, V, Kb, Vt);
  attn_fwd<<<dim3(512), dim3(512), 0, stream>>>(Q, Kb, Vt, outQV, outA);
}

// Round 6
// 627.328 us; speedup vs baseline: 1.3788x; 1.0140x over previous
//
#include <hip/hip_runtime.h>

typedef __bf16 bf16x8 __attribute__((ext_vector_type(8)));
typedef float floatx4 __attribute__((ext_vector_type(4)));
typedef unsigned short ushort8 __attribute__((ext_vector_type(8)));
typedef unsigned short ushort4v __attribute__((ext_vector_type(4)));

#define MFMA(a, b, c) __builtin_amdgcn_mfma_f32_16x16x32_bf16((a), (b), (c), 0, 0, 0)

__device__ __forceinline__ unsigned short f2bf(float x) {
  union { float f; unsigned u; } v; v.f = x;
  unsigned r = v.u + 0x7FFFu + ((v.u >> 16) & 1u);  // RNE; inputs finite
  return (unsigned short)(r >> 16);
}

// ---------------------------------------------------------------------------
// prep (tiled, fully coalesced): one block per (bh, mt) 64x64 tile.
// Outputs swizzled bf16 tiles: 64 rows x 64 bf16; orig 8-elem chunk e of row r
// is stored at slot (e ^ (r&7)) so a LINEAR global_load_lds lands it
// XOR-swizzled in LDS (rule #21 involution).
// K tile: row r = key m (row axis = d).  V tile: row r = d (row axis = m, V^T).
// V transpose goes through an LDS fp32 tile (stride 68: 16B-aligned, <=4-way).
// ---------------------------------------------------------------------------
__global__ __launch_bounds__(256)
void prep(const float* __restrict__ K, const float* __restrict__ V,
          unsigned short* __restrict__ Kb, unsigned short* __restrict__ Vt)
{
  __shared__ float Vl[64 * 68];

  const int bx = blockIdx.x;       // 1024 = 32 bh * 32 mt
  const int mt = bx & 31;
  const int bh = bx >> 5;
  const int b  = bh >> 3, h = bh & 7;
  const int tid = threadIdx.x;
  const int r  = tid >> 2;         // 0..63: row within tile
  const int cq = tid & 3;          // 16-float quarter within row

  const size_t inbase = ((size_t)(b * 2048 + mt * 64 + r) * 8 + h) * 64 + cq * 16;
  unsigned short* ktile = Kb + ((size_t)bh * 32 + mt) * 4096;
  unsigned short* vtile = Vt + ((size_t)bh * 32 + mt) * 4096;

  // ---- K: coalesced read, swizzled write ----
  {
    float4 a0 = *(const float4*)(K + inbase);
    float4 a1 = *(const float4*)(K + inbase + 4);
    float4 a2 = *(const float4*)(K + inbase + 8);
    float4 a3 = *(const float4*)(K + inbase + 12);
    ushort8 o0 = { f2bf(a0.x), f2bf(a0.y), f2bf(a0.z), f2bf(a0.w),
                   f2bf(a1.x), f2bf(a1.y), f2bf(a1.z), f2bf(a1.w) };
    ushort8 o1 = { f2bf(a2.x), f2bf(a2.y), f2bf(a2.z), f2bf(a2.w),
                   f2bf(a3.x), f2bf(a3.y), f2bf(a3.z), f2bf(a3.w) };
    *(ushort8*)(ktile + r * 64 + (((cq * 2)     ^ (r & 7)) * 8)) = o0;
    *(ushort8*)(ktile + r * 64 + (((cq * 2 + 1) ^ (r & 7)) * 8)) = o1;
  }

  // ---- V: coalesced read -> LDS transpose -> swizzled V^T write ----
  {
    float4 a0 = *(const float4*)(V + inbase);
    float4 a1 = *(const float4*)(V + inbase + 4);
    float4 a2 = *(const float4*)(V + inbase + 8);
    float4 a3 = *(const float4*)(V + inbase + 12);
    float vv[16] = { a0.x,a0.y,a0.z,a0.w, a1.x,a1.y,a1.z,a1.w,
                     a2.x,a2.y,a2.z,a2.w, a3.x,a3.y,a3.z,a3.w };
    #pragma unroll
    for (int j = 0; j < 16; ++j) Vl[(cq * 16 + j) * 68 + r] = vv[j];  // Vl[d][m]
  }
  __syncthreads();
  {
    // V^T row d = r, m-chunks cq*16..+15 (16B-aligned: 68*4*r = 272r, 272=17*16)
    float4 w0 = *(const float4*)&Vl[r * 68 + cq * 16];
    float4 w1 = *(const float4*)&Vl[r * 68 + cq * 16 + 4];
    float4 w2 = *(const float4*)&Vl[r * 68 + cq * 16 + 8];
    float4 w3 = *(const float4*)&Vl[r * 68 + cq * 16 + 12];
    ushort8 p0 = { f2bf(w0.x), f2bf(w0.y), f2bf(w0.z), f2bf(w0.w),
                   f2bf(w1.x), f2bf(w1.y), f2bf(w1.z), f2bf(w1.w) };
    ushort8 p1 = { f2bf(w2.x), f2bf(w2.y), f2bf(w2.z), f2bf(w2.w),
                   f2bf(w3.x), f2bf(w3.y), f2bf(w3.z), f2bf(w3.w) };
    *(ushort8*)(vtile + r * 64 + (((cq * 2)     ^ (r & 7)) * 8)) = p0;
    *(ushort8*)(vtile + r * 64 + (((cq * 2 + 1) ^ (r & 7)) * 8)) = p1;
  }
}

// 8-wave cooperative stage: wave w DMAs its 1 KB slice of an 8 KB tile (1 vmem op)
__device__ __forceinline__ void stage1k(const unsigned short* gsrc, unsigned short* lds,
                                        int w, int l)
{
  const char* g = (const char*)gsrc + w * 1024 + l * 16;
  char* sd = (char*)lds + w * 1024;
  __builtin_amdgcn_global_load_lds((const __attribute__((address_space(1))) unsigned int*)g,
                                   (__attribute__((address_space(3))) unsigned int*)sd, 16, 0, 0);
}

// swizzled 16B fragment read from a [64][128B] tile; bo = original byte col (16B-mult)
__device__ __forceinline__ bf16x8 frag(const unsigned short* lds, int r, int bo)
{
  int slot = ((bo >> 4) ^ r) & 7;
  return *(const bf16x8*)((const char*)lds + r * 128 + (slot << 4));
}

__global__ __launch_bounds__(512, 4)
void attn_fwd(const float* __restrict__ Q, const unsigned short* __restrict__ Kb,
              const unsigned short* __restrict__ Vt,
              float* __restrict__ outQV, float* __restrict__ outA)
{
  // 80 KB pool -> exactly 2 blocks/CU (16 waves/CU).
  // [0..16383]      : 4 K tile slots (2 pairs)       (32 KB)
  // [16384..32767]  : 4 V tile slots (2 pairs)       (32 KB)
  // [32768..40959]  : As P-bounce [128 rows][128 B]  (16 KB)
  __shared__ __align__(16) unsigned short pool[40960];
  unsigned short* Kp = pool;
  unsigned short* Vp = pool + 16384;
  unsigned short* As = pool + 32768;

  const int tid = threadIdx.x;
  const int w  = tid >> 6;   // wave 0..7 -> q rows [16w,16w+16)
  const int l  = tid & 63;
  const int c  = l & 15;
  const int q4 = l >> 4;

  // bijective XCD chunk swizzle: grid 512 = 8 XCDs x 64; XCD k owns 4 whole (b,h)
  const int bx = (blockIdx.x & 7) * 64 + (blockIdx.x >> 3);
  const int qt = bx & 15;
  const int bh = bx >> 4;
  const int h  = bh & 7;
  const int b  = bh >> 3;
  const int q0 = qt * 128;

  const float scale = 0.125f * 1.44269504088896340736f;  // 1/sqrt(64) * log2(e)

  const size_t base = (size_t)b * (2048 * 512) + (size_t)h * 64;  // + n*512 + d
  const float* Qb = Q + base + (size_t)q0 * 512;

  const unsigned short* Kt0 = Kb + (size_t)bh * (32 * 4096);
  const unsigned short* Vt0 = Vt + (size_t)bh * (32 * 4096);

  // ---- Q fragments straight to registers (B-operand of swapped QK^T) ----
  bf16x8 bQ0, bQ1;
  {
    const float* qp = Qb + (size_t)(16 * w + c) * 512 + q4 * 8;
    float4 qa0 = *(const float4*)(qp);
    float4 qa1 = *(const float4*)(qp + 4);
    float4 qb0 = *(const float4*)(qp + 32);
    float4 qb1 = *(const float4*)(qp + 36);
    ushort8 t0, t1;
    t0[0]=f2bf(qa0.x*scale); t0[1]=f2bf(qa0.y*scale); t0[2]=f2bf(qa0.z*scale); t0[3]=f2bf(qa0.w*scale);
    t0[4]=f2bf(qa1.x*scale); t0[5]=f2bf(qa1.y*scale); t0[6]=f2bf(qa1.z*scale); t0[7]=f2bf(qa1.w*scale);
    t1[0]=f2bf(qb0.x*scale); t1[1]=f2bf(qb0.y*scale); t1[2]=f2bf(qb0.z*scale); t1[3]=f2bf(qb0.w*scale);
    t1[4]=f2bf(qb1.x*scale); t1[5]=f2bf(qb1.y*scale); t1[6]=f2bf(qb1.z*scale); t1[7]=f2bf(qb1.w*scale);
    bQ0 = __builtin_bit_cast(bf16x8, t0);
    bQ1 = __builtin_bit_cast(bf16x8, t1);
  }

  // ---- pass 1: per-row sum of exp2(S); 2 K tiles per barrier, pair dbuf ----
  stage1k(Kt0,        Kp,        w, l);   // tile 0 -> slot 0
  stage1k(Kt0 + 4096, Kp + 4096, w, l);   // tile 1 -> slot 1
  asm volatile("s_waitcnt vmcnt(0)" ::: "memory");
  __builtin_amdgcn_s_barrier();
  __builtin_amdgcn_sched_barrier(0);

  float lsum[4] = {0.f, 0.f, 0.f, 0.f};
  for (int s = 0; s < 16; ++s) {
    const int pp = s & 1;
    if (s < 15) {  // stage pair s+1 into the other pair-slot
      stage1k(Kt0 + (size_t)(2 * s + 2) * 4096, Kp + (pp ^ 1) * 8192,        w, l);
      stage1k(Kt0 + (size_t)(2 * s + 3) * 4096, Kp + (pp ^ 1) * 8192 + 4096, w, l);
    }
    __builtin_amdgcn_sched_barrier(0);
    __builtin_amdgcn_s_setprio(1);
    #pragma unroll
    for (int j = 0; j < 2; ++j) {
      const unsigned short* Kc = Kp + (pp * 2 + j) * 4096;
      #pragma unroll
      for (int t = 0; t < 4; ++t) {
        bf16x8 aK0 = frag(Kc, t * 16 + c, q4 * 16);
        bf16x8 aK1 = frag(Kc, t * 16 + c, 64 + q4 * 16);
        floatx4 acc = {0.f, 0.f, 0.f, 0.f};
        acc = MFMA(aK0, bQ0, acc);   // swapped: lane holds S[q=16w+c][m=...]
        acc = MFMA(aK1, bQ1, acc);
        #pragma unroll
        for (int i = 0; i < 4; ++i) lsum[i] += __builtin_amdgcn_exp2f(acc[i]);
      }
    }
    __builtin_amdgcn_s_setprio(0);
    __builtin_amdgcn_sched_barrier(0);
    asm volatile("s_waitcnt vmcnt(0)" ::: "memory");  // pair s+1 landed (had full iter)
    __builtin_amdgcn_s_barrier();
    __builtin_amdgcn_sched_barrier(0);
  }
  float rs = (lsum[0] + lsum[1]) + (lsum[2] + lsum[3]);
  rs += __shfl_xor(rs, 16);
  rs += __shfl_xor(rs, 32);
  const float rcp = 1.0f / rs;

  // ---- pass 2: recompute S, write A, accumulate O = A*V; 2 tiles/barrier ----
  floatx4 Oacc[4];
  #pragma unroll
  for (int t = 0; t < 4; ++t) Oacc[t] = (floatx4){0.f, 0.f, 0.f, 0.f};

  const int arow = 16 * w + c;
  float* aRowP = outA + (((size_t)bh * 2048 + q0 + arow) * 2048) + q4 * 4;

  stage1k(Kt0,        Kp,        w, l);
  stage1k(Kt0 + 4096, Kp + 4096, w, l);
  stage1k(Vt0,        Vp,        w, l);
  stage1k(Vt0 + 4096, Vp + 4096, w, l);
  asm volatile("s_waitcnt vmcnt(0)" ::: "memory");
  __builtin_amdgcn_s_barrier();
  __builtin_amdgcn_sched_barrier(0);

  for (int s = 0; s < 16; ++s) {
    const int pp = s & 1;
    if (s < 15) {
      stage1k(Kt0 + (size_t)(2 * s + 2) * 4096, Kp + (pp ^ 1) * 8192,        w, l);
      stage1k(Kt0 + (size_t)(2 * s + 3) * 4096, Kp + (pp ^ 1) * 8192 + 4096, w, l);
      stage1k(Vt0 + (size_t)(2 * s + 2) * 4096, Vp + (pp ^ 1) * 8192,        w, l);
      stage1k(Vt0 + (size_t)(2 * s + 3) * 4096, Vp + (pp ^ 1) * 8192 + 4096, w, l);
    }
    __builtin_amdgcn_sched_barrier(0);   // pin [4 DMA] before this iter's stores
    __builtin_amdgcn_s_setprio(1);
    #pragma unroll
    for (int j = 0; j < 2; ++j) {
      const unsigned short* Kc = Kp + (pp * 2 + j) * 4096;
      const unsigned short* Vc = Vp + (pp * 2 + j) * 4096;
      const int mc = (2 * s + j) * 64;
      #pragma unroll
      for (int t = 0; t < 4; ++t) {
        bf16x8 aK0 = frag(Kc, t * 16 + c, q4 * 16);
        bf16x8 aK1 = frag(Kc, t * 16 + c, 64 + q4 * 16);
        floatx4 acc = {0.f, 0.f, 0.f, 0.f};
        acc = MFMA(aK0, bQ0, acc);
        acc = MFMA(aK1, bQ1, acc);
        floatx4 av;
        av[0] = __builtin_amdgcn_exp2f(acc[0]) * rcp;
        av[1] = __builtin_amdgcn_exp2f(acc[1]) * rcp;
        av[2] = __builtin_amdgcn_exp2f(acc[2]) * rcp;
        av[3] = __builtin_amdgcn_exp2f(acc[3]) * rcp;
        *(floatx4*)(aRowP + mc + t * 16) = av;   // cached store; L2 merges lines
        // As[arow][t*16 + q4*4 .. +3], 16B-slot XOR swizzle (b64 writes)
        ushort4v us = { f2bf(av[0]), f2bf(av[1]), f2bf(av[2]), f2bf(av[3]) };
        int bo = t * 32 + q4 * 8;                // byte col within row
        int slot = ((bo >> 4) ^ arow) & 7;
        *(ushort4v*)((char*)As + arow * 128 + (slot << 4) + (bo & 15)) = us;
      }
      // PV: aP = own wave's P rows (same-wave LDS RAW; compiler inserts lgkmcnt)
      {
        int s0 = ((q4) ^ arow) & 7;              // (q4*16)>>4 = q4
        int s1 = ((4 + q4) ^ arow) & 7;          // (64+q4*16)>>4 = 4+q4
        bf16x8 aP0 = *(const bf16x8*)((const char*)As + arow * 128 + (s0 << 4));
        bf16x8 aP1 = *(const bf16x8*)((const char*)As + arow * 128 + (s1 << 4));
        #pragma unroll
        for (int t = 0; t < 4; ++t) {
          bf16x8 bV0 = frag(Vc, t * 16 + c, q4 * 16);
          bf16x8 bV1 = frag(Vc, t * 16 + c, 64 + q4 * 16);
          Oacc[t] = MFMA(aP0, bV0, Oacc[t]);
          Oacc[t] = MFMA(aP1, bV1, Oacc[t]);
        }
      }
    }
    __builtin_amdgcn_s_setprio(0);
    // FIFO: outstanding = [pair(s+1) DMA x4][this iter's stores x8]; vmcnt(8)
    // retires the DMA, leaves stores in flight across the barrier.
    __builtin_amdgcn_sched_barrier(0);
    asm volatile("s_waitcnt vmcnt(8)" ::: "memory");
    __builtin_amdgcn_s_barrier();
    __builtin_amdgcn_sched_barrier(0);
  }

  // ---- write queried_values [B,N,H,D] ----
  #pragma unroll
  for (int t = 0; t < 4; ++t) {
    #pragma unroll
    for (int i = 0; i < 4; ++i) {
      outQV[base + (size_t)(q0 + 16 * w + q4 * 4 + i) * 512 + t * 16 + c] = Oacc[t][i];
    }
  }
}

extern "C" void kernel_launch(void* const* d_in, const int* in_sizes, int n_in,
                              void* d_out, int out_size, void* d_ws, size_t ws_size,
                              hipStream_t stream)
{
  const float* Q = (const float*)d_in[0];
  const float* K = (const float*)d_in[1];
  const float* V = (const float*)d_in[2];
  float* outQV = (float*)d_out;                 // [4,2048,8,64] = 4194304 floats
  float* outA  = (float*)d_out + 4194304;       // [4,8,2048,2048]

  unsigned short* Kb = (unsigned short*)d_ws;           // 8 MB swizzled bf16 K tiles
  unsigned short* Vt = (unsigned short*)d_ws + 4194304; // 8 MB swizzled bf16 V^T tiles

  prep<<<dim3(1024), dim3(256), 0, stream>>>(K, V, Kb, Vt);
  attn_fwd<<<dim3(512), dim3(512), 0, stream>>>(Q, Kb, Vt, outQV, outA);
}